// Round 7
// baseline (854.900 us; speedup 1.0000x reference)
//
#include <hip/hip_runtime.h>

typedef _Float16 h16;
typedef __attribute__((ext_vector_type(8))) _Float16 half8;
typedef __attribute__((ext_vector_type(4))) _Float16 half4;
typedef __attribute__((ext_vector_type(4))) float f32x4;
typedef __attribute__((ext_vector_type(16))) float f32x16;

// weight fragment offsets in d_ws (fp16 elements) — same conv format as R4..R6
constexpr size_t OFF_P0 = 0;        // [64 ][256]
constexpr size_t OFF_P1 = 16384;    // [256][256]
constexpr size_t OFF_P2 = 81920;
constexpr size_t OFF_P3 = 147456;
constexpr size_t OFF_P4 = 212992;
constexpr size_t OFF_P5 = 278528;   // [320][256], ROTATED: rows 0..255 = h-part, 256..319 = ep-part
constexpr size_t OFF_P6 = 360448;
constexpr size_t OFF_P7 = 425984;
constexpr size_t OFF_FEAT = 491520; // [256][256]
constexpr size_t OFF_VIEWS = 557056;// [288][128] (rows 0..255 feat, 256..282 ev, 283..287 zero)

__device__ __forceinline__ f32x16 mfma32(half8 a, half8 b, f32x16 c) {
  return __builtin_amdgcn_mfma_f32_32x32x16_f16(a, b, c, 0, 0, 0);
}
__device__ __forceinline__ half8 ldfrag(const h16* __restrict__ base, int frag, int l) {
  return *(const half8*)(base + (size_t)frag * 512 + (size_t)l * 8);
}
__device__ __forceinline__ half8 ldsfrag(const h16* __restrict__ base, int frag, int l) {
  return *(const half8*)(base + frag * 512 + l * 8);
}

// fp32 [K][N] row-major -> pre-swizzled fp16 fragments for 32x32x16 (unchanged).
__global__ void convw_kernel(const float* __restrict__ src, h16* __restrict__ dst,
                             int Ksrc, int N, int Kp, int p, int npad, int rot) {
  int t = blockIdx.x * 256 + threadIdx.x;
  int nfrags = (Kp >> 4) * (N >> 5);
  int frag = t >> 6;
  if (frag >= nfrags) return;
  int l = t & 63;
  int ntiles = N >> 5;
  int kt = frag / ntiles;
  int nt = frag - kt * ntiles;
  int col = nt * 32 + (l & 31);
  int kbase = kt * 16 + (l >> 5) * 8;
  half8 v;
#pragma unroll
  for (int j = 0; j < 8; ++j) {
    int pr = kbase + j + rot;
    if (pr >= Kp) pr -= Kp;
    float x = 0.f;
    if (pr < p) {
      x = src[(size_t)pr * N + col];
    } else if (pr >= p + npad) {
      int r = pr - npad;
      if (r < Ksrc) x = src[(size_t)r * N + col];
    }
    v[j] = (h16)x;
  }
  *(half8*)(dst + (size_t)frag * 512 + (size_t)l * 8) = v;
}

struct Params {
  const float* pts;
  const float* views;
  const h16* wf;
  const float* pb[8];
  const float* views_b;
  const float* feat_b;
  const float* alpha_w;
  const float* alpha_b;
  const float* rgb_w;
  const float* rgb_b;
  float* out;
};

// Epilogue: one 32x32 tile -> frag-major LDS (layout verified on HW in R6).
// Element (row,col): frag=(row>>5)*16+(col>>4), slot=(row&31)+32*((col>>3)&1), elem=col&7.
template <bool RELU>
__device__ __forceinline__ void epiW(h16* __restrict__ Y, const f32x16& A,
                                     int rt, int ct, const float* __restrict__ bias,
                                     int lr, int lh) {
#pragma unroll
  for (int g = 0; g < 4; ++g) {
    int col0 = ct * 32 + g * 8 + lh * 4;
    f32x4 bv = *(const f32x4*)(bias + col0);
    half4 pk;
#pragma unroll
    for (int i = 0; i < 4; ++i) {
      float v = A[g * 4 + i] + bv[i];
      if (RELU) v = fmaxf(v, 0.f);
      pk[i] = (h16)v;
    }
    *(half4*)(Y + (rt * 16 + ct * 2 + (g >> 1)) * 512 + ((g & 1) * 32 + lr) * 8 + lh * 4) = pk;
  }
}

// embed value for column c given a point (x0,x1,x2)
__device__ __forceinline__ float embed_col(int c, float x0, float x1, float x2) {
  if (c < 3) return c == 0 ? x0 : (c == 1 ? x1 : x2);
  if (c >= 63) return 0.f;
  int t = c - 3;
  int f = t / 6, rem = t - f * 6;
  int d = rem >= 3 ? rem - 3 : rem;
  float x = (d == 0 ? x0 : (d == 1 ? x1 : x2)) * (float)(1 << f);
  return (rem < 3) ? sinf(x) : cosf(x);
}

// One trunk layer, M=256, N=256, in-place on h.
// Wave (rt = w&7, ch = w>>3): 1 row-tile x 4 col-tiles, ct0 = ch*4.
// EXTEP (L5): 4 extra kts from register ep frags.
template <bool RELU, bool EXTEP>
__device__ __forceinline__ void layerT(h16* __restrict__ h,
                                       const h16* __restrict__ wcur,
                                       const float* __restrict__ bias,
                                       const half8* epf,  // 4 frags (only if EXTEP)
                                       int rt, int ct0, int l, int lr, int lh) {
  f32x16 a0 = (f32x16)0.f, a1 = (f32x16)0.f, a2 = (f32x16)0.f, a3 = (f32x16)0.f;
#pragma unroll
  for (int kt = 0; kt < 16; ++kt) {
    half8 x = ldsfrag(h, rt * 16 + kt, l);
    half8 w0 = ldfrag(wcur, kt * 8 + ct0 + 0, l);
    half8 w1 = ldfrag(wcur, kt * 8 + ct0 + 1, l);
    half8 w2 = ldfrag(wcur, kt * 8 + ct0 + 2, l);
    half8 w3 = ldfrag(wcur, kt * 8 + ct0 + 3, l);
    a0 = mfma32(w0, x, a0);
    a1 = mfma32(w1, x, a1);
    a2 = mfma32(w2, x, a2);
    a3 = mfma32(w3, x, a3);
  }
  if (EXTEP) {
#pragma unroll
    for (int j = 0; j < 4; ++j) {
      half8 x = epf[j];
      half8 w0 = ldfrag(wcur, (16 + j) * 8 + ct0 + 0, l);
      half8 w1 = ldfrag(wcur, (16 + j) * 8 + ct0 + 1, l);
      half8 w2 = ldfrag(wcur, (16 + j) * 8 + ct0 + 2, l);
      half8 w3 = ldfrag(wcur, (16 + j) * 8 + ct0 + 3, l);
      a0 = mfma32(w0, x, a0);
      a1 = mfma32(w1, x, a1);
      a2 = mfma32(w2, x, a2);
      a3 = mfma32(w3, x, a3);
    }
  }
  __syncthreads();  // all reads of h complete
  epiW<RELU>(h, a0, rt, ct0 + 0, bias, lr, lh);
  epiW<RELU>(h, a1, rt, ct0 + 1, bias, lr, lh);
  epiW<RELU>(h, a2, rt, ct0 + 2, bias, lr, lh);
  epiW<RELU>(h, a3, rt, ct0 + 3, bias, lr, lh);
  __syncthreads();
}

__global__ __launch_bounds__(1024, 4) void nerf_kernel(Params P) {
  __shared__ __align__(16) h16 h[128 * 512];   // 128 KB, frag-major [rt*16 + kt]
  __shared__ __align__(16) h16 evp[128];       // 4 rays x 32
  __shared__ float alpha_s[256];

  const int tid = threadIdx.x;
  const int w = tid >> 6, l = tid & 63;
  const int lr = l & 31, lh = l >> 5;
  const int rt = w & 7, ch = w >> 3;
  const int ct0 = ch * 4;
  const h16* wf = P.wf;
  const size_t row_base = (size_t)blockIdx.x * 256;

  // ---- embeddings into per-wave registers (row = rt*32 + lr) ----
  const float* ps = P.pts + (row_base + rt * 32 + lr) * 3;
  const float x0 = ps[0], x1 = ps[1], x2 = ps[2];
  half8 epf[4];
#pragma unroll
  for (int kt = 0; kt < 4; ++kt) {
    half8 v;
#pragma unroll
    for (int j = 0; j < 8; ++j)
      v[j] = (h16)embed_col(kt * 16 + lh * 8 + j, x0, x1, x2);
    epf[kt] = v;
  }
  // views embedding (4 rays per block) into LDS
  if (tid < 128) {
    const int r = tid >> 5, idx = tid & 31;
    float v = 0.f;
    if (idx < 27) {
      if (idx < 3) {
        v = P.views[((size_t)blockIdx.x * 4 + r) * 3 + idx];
      } else {
        const int f = (idx - 3) / 6, rem = (idx - 3) % 6, d = rem % 3;
        const float x = P.views[((size_t)blockIdx.x * 4 + r) * 3 + d] * (float)(1 << f);
        v = (rem < 3) ? sinf(x) : cosf(x);
      }
    }
    evp[tid] = (h16)v;
  }

  // ---- L0: K=64 from register ep frags -> h ----
  {
    f32x16 a0 = (f32x16)0.f, a1 = (f32x16)0.f, a2 = (f32x16)0.f, a3 = (f32x16)0.f;
#pragma unroll
    for (int kt = 0; kt < 4; ++kt) {
      half8 x = epf[kt];
      half8 w0 = ldfrag(wf + OFF_P0, kt * 8 + ct0 + 0, l);
      half8 w1 = ldfrag(wf + OFF_P0, kt * 8 + ct0 + 1, l);
      half8 w2 = ldfrag(wf + OFF_P0, kt * 8 + ct0 + 2, l);
      half8 w3 = ldfrag(wf + OFF_P0, kt * 8 + ct0 + 3, l);
      a0 = mfma32(w0, x, a0);
      a1 = mfma32(w1, x, a1);
      a2 = mfma32(w2, x, a2);
      a3 = mfma32(w3, x, a3);
    }
    epiW<true>(h, a0, rt, ct0 + 0, P.pb[0], lr, lh);
    epiW<true>(h, a1, rt, ct0 + 1, P.pb[0], lr, lh);
    epiW<true>(h, a2, rt, ct0 + 2, P.pb[0], lr, lh);
    epiW<true>(h, a3, rt, ct0 + 3, P.pb[0], lr, lh);
    __syncthreads();
  }

  // ---- trunk L1..L7 (in-place) ----
  layerT<true, false>(h, wf + OFF_P1, P.pb[1], epf, rt, ct0, l, lr, lh);
  layerT<true, false>(h, wf + OFF_P2, P.pb[2], epf, rt, ct0, l, lr, lh);
  layerT<true, false>(h, wf + OFF_P3, P.pb[3], epf, rt, ct0, l, lr, lh);
  layerT<true, false>(h, wf + OFF_P4, P.pb[4], epf, rt, ct0, l, lr, lh);
  layerT<true, true>(h, wf + OFF_P5, P.pb[5], epf, rt, ct0, l, lr, lh);  // K=320
  layerT<true, false>(h, wf + OFF_P6, P.pb[6], epf, rt, ct0, l, lr, lh);
  layerT<true, false>(h, wf + OFF_P7, P.pb[7], epf, rt, ct0, l, lr, lh);

  // ---- alpha = h @ alpha_w + alpha_b (before feature overwrites h) ----
  {
    const int s = tid >> 2, q = tid & 3;
    float sum = 0.f;
#pragma unroll
    for (int j = 0; j < 8; ++j) {
      int k0 = q * 64 + j * 8;
      half8 hv = *(const half8*)(h + ((s >> 5) * 16 + (k0 >> 4)) * 512 +
                                 ((s & 31) + 32 * ((k0 >> 3) & 1)) * 8);
      f32x4 w0 = *(const f32x4*)(P.alpha_w + k0);
      f32x4 w1 = *(const f32x4*)(P.alpha_w + k0 + 4);
      sum += (float)hv[0] * w0[0] + (float)hv[1] * w0[1] + (float)hv[2] * w0[2] + (float)hv[3] * w0[3];
      sum += (float)hv[4] * w1[0] + (float)hv[5] * w1[1] + (float)hv[6] * w1[2] + (float)hv[7] * w1[3];
    }
    sum += __shfl_xor(sum, 1);
    sum += __shfl_xor(sum, 2);
    if (q == 0) alpha_s[s] = sum + P.alpha_b[0];
  }

  // ---- feature = h @ feat_w + feat_b (no relu), in place ----
  layerT<false, false>(h, wf + OFF_FEAT, P.feat_b, epf, rt, ct0, l, lr, lh);

  // ---- h2 = relu([feature, ev] @ views_w + views_b) -> h cols 0..127 ----
  // wave: same rt, col-pair cv0 = ch*2 (N=128 -> 4 col-tiles).
  {
    const int cv0 = ch * 2;
    const h16* wV = wf + OFF_VIEWS;
    f32x16 b0 = (f32x16)0.f, b1 = (f32x16)0.f;
#pragma unroll
    for (int kt = 0; kt < 16; ++kt) {
      half8 x = ldsfrag(h, rt * 16 + kt, l);
      half8 w0 = ldfrag(wV, kt * 4 + cv0 + 0, l);
      half8 w1 = ldfrag(wV, kt * 4 + cv0 + 1, l);
      b0 = mfma32(w0, x, b0);
      b1 = mfma32(w1, x, b1);
    }
#pragma unroll
    for (int kt = 16; kt < 18; ++kt) {
      half8 x = *(const half8*)(evp + (rt >> 1) * 32 + (kt - 16) * 16 + lh * 8);
      half8 w0 = ldfrag(wV, kt * 4 + cv0 + 0, l);
      half8 w1 = ldfrag(wV, kt * 4 + cv0 + 1, l);
      b0 = mfma32(w0, x, b0);
      b1 = mfma32(w1, x, b1);
    }
    __syncthreads();
    epiW<true>(h, b0, rt, cv0 + 0, P.views_b, lr, lh);
    epiW<true>(h, b1, rt, cv0 + 1, P.views_b, lr, lh);
    __syncthreads();
  }

  // ---- rgb + output ----
  {
    const int s = tid >> 2, q = tid & 3;
    float r0 = 0.f, r1 = 0.f, r2 = 0.f;
#pragma unroll
    for (int j = 0; j < 4; ++j) {
      int k0 = q * 32 + j * 8;
      half8 hv = *(const half8*)(h + ((s >> 5) * 16 + (k0 >> 4)) * 512 +
                                 ((s & 31) + 32 * ((k0 >> 3) & 1)) * 8);
#pragma unroll
      for (int i = 0; i < 8; ++i) {
        const float f = (float)hv[i];
        r0 += f * P.rgb_w[(k0 + i) * 3 + 0];
        r1 += f * P.rgb_w[(k0 + i) * 3 + 1];
        r2 += f * P.rgb_w[(k0 + i) * 3 + 2];
      }
    }
    r0 += __shfl_xor(r0, 1); r0 += __shfl_xor(r0, 2);
    r1 += __shfl_xor(r1, 1); r1 += __shfl_xor(r1, 2);
    r2 += __shfl_xor(r2, 1); r2 += __shfl_xor(r2, 2);
    if (q == 0) {
      float4 o;
      o.x = r0 + P.rgb_b[0];
      o.y = r1 + P.rgb_b[1];
      o.z = r2 + P.rgb_b[2];
      o.w = alpha_s[s];
      *(float4*)(P.out + (row_base + s) * 4) = o;
    }
  }
}

extern "C" void kernel_launch(void* const* d_in, const int* in_sizes, int n_in,
                              void* d_out, int out_size, void* d_ws, size_t ws_size,
                              hipStream_t stream) {
  h16* wsw = (h16*)d_ws;
  auto conv = [&](int idx, int Ksrc, int N, int Kp, int p, int npad, int rot, size_t off) {
    int nfrags = (Kp / 16) * (N / 32);
    int total = nfrags * 64;
    convw_kernel<<<(total + 255) / 256, 256, 0, stream>>>(
        (const float*)d_in[idx], wsw + off, Ksrc, N, Kp, p, npad, rot);
  };
  conv(2, 63, 256, 64, 63, 1, 0, OFF_P0);
  conv(4, 256, 256, 256, 256, 0, 0, OFF_P1);
  conv(6, 256, 256, 256, 256, 0, 0, OFF_P2);
  conv(8, 256, 256, 256, 256, 0, 0, OFF_P3);
  conv(10, 256, 256, 256, 256, 0, 0, OFF_P4);
  conv(12, 319, 256, 320, 63, 1, 64, OFF_P5);   // rotated: h-part first
  conv(14, 256, 256, 256, 256, 0, 0, OFF_P6);
  conv(16, 256, 256, 256, 256, 0, 0, OFF_P7);
  conv(20, 256, 256, 256, 256, 0, 0, OFF_FEAT);
  conv(18, 283, 128, 288, 283, 5, 0, OFF_VIEWS);

  Params P;
  P.pts = (const float*)d_in[0];
  P.views = (const float*)d_in[1];
  P.wf = wsw;
  for (int i = 0; i < 8; ++i) P.pb[i] = (const float*)d_in[3 + 2 * i];
  P.views_b = (const float*)d_in[19];
  P.feat_b = (const float*)d_in[21];
  P.alpha_w = (const float*)d_in[22];
  P.alpha_b = (const float*)d_in[23];
  P.rgb_w = (const float*)d_in[24];
  P.rgb_b = (const float*)d_in[25];
  P.out = (float*)d_out;

  nerf_kernel<<<1024, 1024, 0, stream>>>(P);
}

// Round 8
// 487.989 us; speedup vs baseline: 1.7519x; 1.7519x over previous
//
#include <hip/hip_runtime.h>

typedef _Float16 h16;
typedef __attribute__((ext_vector_type(8))) _Float16 half8;
typedef __attribute__((ext_vector_type(4))) _Float16 half4;
typedef __attribute__((ext_vector_type(4))) float f32x4;
typedef __attribute__((ext_vector_type(16))) float f32x16;

// weight fragment offsets in d_ws (fp16 elements) — same conv format as R4..R7
constexpr size_t OFF_P0 = 0;        // [64 ][256]
constexpr size_t OFF_P1 = 16384;    // [256][256]
constexpr size_t OFF_P2 = 81920;
constexpr size_t OFF_P3 = 147456;
constexpr size_t OFF_P4 = 212992;
constexpr size_t OFF_P5 = 278528;   // [320][256], ROTATED: rows 0..255 = h-part, 256..319 = ep-part
constexpr size_t OFF_P6 = 360448;
constexpr size_t OFF_P7 = 425984;
constexpr size_t OFF_FEAT = 491520; // [256][256]
constexpr size_t OFF_VIEWS = 557056;// [288][128] (rows 0..255 feat, 256..282 ev, 283..287 zero)

__device__ __forceinline__ f32x16 mfma32(half8 a, half8 b, f32x16 c) {
  return __builtin_amdgcn_mfma_f32_32x32x16_f16(a, b, c, 0, 0, 0);
}
__device__ __forceinline__ half8 ldfrag(const h16* __restrict__ base, int frag, int l) {
  return *(const half8*)(base + (size_t)frag * 512 + (size_t)l * 8);
}
__device__ __forceinline__ half8 ldsfrag(const h16* __restrict__ base, int frag, int l) {
  return *(const half8*)(base + frag * 512 + l * 8);
}

// fp32 [K][N] row-major -> pre-swizzled fp16 fragments for 32x32x16 (unchanged).
__global__ void convw_kernel(const float* __restrict__ src, h16* __restrict__ dst,
                             int Ksrc, int N, int Kp, int p, int npad, int rot) {
  int t = blockIdx.x * 256 + threadIdx.x;
  int nfrags = (Kp >> 4) * (N >> 5);
  int frag = t >> 6;
  if (frag >= nfrags) return;
  int l = t & 63;
  int ntiles = N >> 5;
  int kt = frag / ntiles;
  int nt = frag - kt * ntiles;
  int col = nt * 32 + (l & 31);
  int kbase = kt * 16 + (l >> 5) * 8;
  half8 v;
#pragma unroll
  for (int j = 0; j < 8; ++j) {
    int pr = kbase + j + rot;
    if (pr >= Kp) pr -= Kp;
    float x = 0.f;
    if (pr < p) {
      x = src[(size_t)pr * N + col];
    } else if (pr >= p + npad) {
      int r = pr - npad;
      if (r < Ksrc) x = src[(size_t)r * N + col];
    }
    v[j] = (h16)x;
  }
  *(half8*)(dst + (size_t)frag * 512 + (size_t)l * 8) = v;
}

struct Params {
  const float* pts;
  const float* views;
  const h16* wf;
  const float* pb[8];
  const float* views_b;
  const float* feat_b;
  const float* alpha_w;
  const float* alpha_b;
  const float* rgb_w;
  const float* rgb_b;
  float* out;
};

// Epilogue: one 32x32 tile -> frag-major LDS (HW-verified layout, R6/R7).
// Element (row,col): frag=(row>>5)*NF+(col>>4), slot=(row&31)+32*((col>>3)&1), elem=col&7.
template <bool RELU>
__device__ __forceinline__ void epiW(h16* __restrict__ Y, const f32x16& A,
                                     int rt, int ct, const float* __restrict__ bias,
                                     int lr, int lh) {
#pragma unroll
  for (int g = 0; g < 4; ++g) {
    int col0 = ct * 32 + g * 8 + lh * 4;
    f32x4 bv = *(const f32x4*)(bias + col0);
    half4 pk;
#pragma unroll
    for (int i = 0; i < 4; ++i) {
      float v = A[g * 4 + i] + bv[i];
      if (RELU) v = fmaxf(v, 0.f);
      pk[i] = (h16)v;
    }
    *(half4*)(Y + (rt * 16 + ct * 2 + (g >> 1)) * 512 + ((g & 1) * 32 + lr) * 8 + lh * 4) = pk;
  }
}

// embed value for column c given a point (x0,x1,x2)
__device__ __forceinline__ float embed_col(int c, float x0, float x1, float x2) {
  if (c < 3) return c == 0 ? x0 : (c == 1 ? x1 : x2);
  if (c >= 63) return 0.f;
  int t = c - 3;
  int f = t / 6, rem = t - f * 6;
  int d = rem >= 3 ? rem - 3 : rem;
  float x = (d == 0 ? x0 : (d == 1 ? x1 : x2)) * (float)(1 << f);
  return (rem < 3) ? sinf(x) : cosf(x);
}

// One trunk layer, M=128, N=256, in-place on h (frag-major [rt*16+kt], rt 0..3).
// Wave (rt = w&3, cq = w>>2): 1 row-tile x 2 col-tiles (ct0 = cq*2).
// EXTEP (L5): 4 extra kts read from the ep LDS buffer (frag rt*4+j).
template <bool RELU, bool EXTEP>
__device__ __forceinline__ void layerT(h16* __restrict__ h,
                                       const h16* __restrict__ ep,
                                       const h16* __restrict__ wcur,
                                       const float* __restrict__ bias,
                                       int rt, int ct0, int l, int lr, int lh) {
  f32x16 a0 = (f32x16)0.f, a1 = (f32x16)0.f;
#pragma unroll
  for (int kt = 0; kt < 16; ++kt) {
    half8 x = ldsfrag(h, rt * 16 + kt, l);
    half8 w0 = ldfrag(wcur, kt * 8 + ct0 + 0, l);
    half8 w1 = ldfrag(wcur, kt * 8 + ct0 + 1, l);
    a0 = mfma32(w0, x, a0);
    a1 = mfma32(w1, x, a1);
  }
  if (EXTEP) {
#pragma unroll
    for (int j = 0; j < 4; ++j) {
      half8 x = ldsfrag(ep, rt * 4 + j, l);
      half8 w0 = ldfrag(wcur, (16 + j) * 8 + ct0 + 0, l);
      half8 w1 = ldfrag(wcur, (16 + j) * 8 + ct0 + 1, l);
      a0 = mfma32(w0, x, a0);
      a1 = mfma32(w1, x, a1);
    }
  }
  __syncthreads();  // all reads of h complete before overwrite
  epiW<RELU>(h, a0, rt, ct0 + 0, bias, lr, lh);
  epiW<RELU>(h, a1, rt, ct0 + 1, bias, lr, lh);
  __syncthreads();
}

__global__ __launch_bounds__(1024, 4) void nerf_kernel(Params P) {
  __shared__ __align__(16) h16 h[64 * 512];   // 64 KB, frag-major [rt*16 + kt]
  __shared__ __align__(16) h16 ep[16 * 512];  // 16 KB, frag-major [rt*4 + kt]
  __shared__ __align__(16) h16 evp[64];       // 2 rays x 32
  __shared__ float alpha_s[128];

  const int tid = threadIdx.x;
  const int w = tid >> 6, l = tid & 63;
  const int lr = l & 31, lh = l >> 5;
  const int rt = w & 3, cq = w >> 2;
  const int ct0 = cq * 2;
  const h16* wf = P.wf;
  const size_t row_base = (size_t)blockIdx.x * 128;

  // ---- embeddings -> ep LDS (frag-major). thread (s=tid>>3, q=tid&7): 8 cols ----
  {
    const int s = tid >> 3, q = tid & 7;
    const float* ps = P.pts + (row_base + s) * 3;
    const float x0 = ps[0], x1 = ps[1], x2 = ps[2];
    half8 v;
#pragma unroll
    for (int j = 0; j < 8; ++j)
      v[j] = (h16)embed_col(q * 8 + j, x0, x1, x2);
    *(half8*)(ep + ((s >> 5) * 4 + (q >> 1)) * 512 + ((s & 31) + 32 * (q & 1)) * 8) = v;
  }
  if (tid < 64) {
    const int r = tid >> 5, idx = tid & 31;
    float v = 0.f;
    if (idx < 27) {
      if (idx < 3) {
        v = P.views[((size_t)blockIdx.x * 2 + r) * 3 + idx];
      } else {
        const int f = (idx - 3) / 6, rem = (idx - 3) % 6, d = rem % 3;
        const float x = P.views[((size_t)blockIdx.x * 2 + r) * 3 + d] * (float)(1 << f);
        v = (rem < 3) ? sinf(x) : cosf(x);
      }
    }
    evp[tid] = (h16)v;
  }
  __syncthreads();

  // ---- L0: K=64 from ep ----
  {
    f32x16 a0 = (f32x16)0.f, a1 = (f32x16)0.f;
#pragma unroll
    for (int kt = 0; kt < 4; ++kt) {
      half8 x = ldsfrag(ep, rt * 4 + kt, l);
      half8 w0 = ldfrag(wf + OFF_P0, kt * 8 + ct0 + 0, l);
      half8 w1 = ldfrag(wf + OFF_P0, kt * 8 + ct0 + 1, l);
      a0 = mfma32(w0, x, a0);
      a1 = mfma32(w1, x, a1);
    }
    epiW<true>(h, a0, rt, ct0 + 0, P.pb[0], lr, lh);
    epiW<true>(h, a1, rt, ct0 + 1, P.pb[0], lr, lh);
    __syncthreads();
  }

  // ---- trunk L1..L7 (in-place) ----
  layerT<true, false>(h, ep, wf + OFF_P1, P.pb[1], rt, ct0, l, lr, lh);
  layerT<true, false>(h, ep, wf + OFF_P2, P.pb[2], rt, ct0, l, lr, lh);
  layerT<true, false>(h, ep, wf + OFF_P3, P.pb[3], rt, ct0, l, lr, lh);
  layerT<true, false>(h, ep, wf + OFF_P4, P.pb[4], rt, ct0, l, lr, lh);
  layerT<true, true>(h, ep, wf + OFF_P5, P.pb[5], rt, ct0, l, lr, lh);  // K=320
  layerT<true, false>(h, ep, wf + OFF_P6, P.pb[6], rt, ct0, l, lr, lh);
  layerT<true, false>(h, ep, wf + OFF_P7, P.pb[7], rt, ct0, l, lr, lh);

  // ---- alpha = h @ alpha_w + alpha_b (before feature overwrites h) ----
  {
    const int s = tid >> 3, q = tid & 7;
    float sum = 0.f;
#pragma unroll
    for (int j = 0; j < 4; ++j) {
      int k0 = q * 32 + j * 8;
      half8 hv = *(const half8*)(h + ((s >> 5) * 16 + (k0 >> 4)) * 512 +
                                 ((s & 31) + 32 * ((k0 >> 3) & 1)) * 8);
      f32x4 w0 = *(const f32x4*)(P.alpha_w + k0);
      f32x4 w1 = *(const f32x4*)(P.alpha_w + k0 + 4);
      sum += (float)hv[0] * w0[0] + (float)hv[1] * w0[1] + (float)hv[2] * w0[2] + (float)hv[3] * w0[3];
      sum += (float)hv[4] * w1[0] + (float)hv[5] * w1[1] + (float)hv[6] * w1[2] + (float)hv[7] * w1[3];
    }
    sum += __shfl_xor(sum, 1);
    sum += __shfl_xor(sum, 2);
    sum += __shfl_xor(sum, 4);
    if (q == 0) alpha_s[s] = sum + P.alpha_b[0];
  }

  // ---- feature = h @ feat_w + feat_b (no relu), in place ----
  layerT<false, false>(h, ep, wf + OFF_FEAT, P.feat_b, rt, ct0, l, lr, lh);

  // ---- h2 = relu([feature, ev] @ views_w + views_b) -> h frags [rt*16 + 0..7] ----
  // wave: rt = w&3, single col-tile ct = w>>2 (N=128 -> 4 col-tiles).
  {
    const int ct = cq;
    const h16* wV = wf + OFF_VIEWS;
    f32x16 b = (f32x16)0.f;
#pragma unroll
    for (int kt = 0; kt < 16; ++kt) {
      half8 x = ldsfrag(h, rt * 16 + kt, l);
      half8 wv = ldfrag(wV, kt * 4 + ct, l);
      b = mfma32(wv, x, b);
    }
#pragma unroll
    for (int kt = 16; kt < 18; ++kt) {
      half8 x = *(const half8*)(evp + (rt >> 1) * 32 + (kt - 16) * 16 + lh * 8);
      half8 wv = ldfrag(wV, kt * 4 + ct, l);
      b = mfma32(wv, x, b);
    }
    __syncthreads();
    epiW<true>(h, b, rt, ct, P.views_b, lr, lh);
    __syncthreads();
  }

  // ---- rgb + output ----
  {
    const int s = tid >> 3, q = tid & 7;
    float r0 = 0.f, r1 = 0.f, r2 = 0.f;
#pragma unroll
    for (int j = 0; j < 2; ++j) {
      int k0 = q * 16 + j * 8;
      half8 hv = *(const half8*)(h + ((s >> 5) * 16 + (k0 >> 4)) * 512 +
                                 ((s & 31) + 32 * ((k0 >> 3) & 1)) * 8);
#pragma unroll
      for (int i = 0; i < 8; ++i) {
        const float f = (float)hv[i];
        r0 += f * P.rgb_w[(k0 + i) * 3 + 0];
        r1 += f * P.rgb_w[(k0 + i) * 3 + 1];
        r2 += f * P.rgb_w[(k0 + i) * 3 + 2];
      }
    }
    r0 += __shfl_xor(r0, 1); r0 += __shfl_xor(r0, 2); r0 += __shfl_xor(r0, 4);
    r1 += __shfl_xor(r1, 1); r1 += __shfl_xor(r1, 2); r1 += __shfl_xor(r1, 4);
    r2 += __shfl_xor(r2, 1); r2 += __shfl_xor(r2, 2); r2 += __shfl_xor(r2, 4);
    if (q == 0) {
      float4 o;
      o.x = r0 + P.rgb_b[0];
      o.y = r1 + P.rgb_b[1];
      o.z = r2 + P.rgb_b[2];
      o.w = alpha_s[s];
      *(float4*)(P.out + (row_base + s) * 4) = o;
    }
  }
}

extern "C" void kernel_launch(void* const* d_in, const int* in_sizes, int n_in,
                              void* d_out, int out_size, void* d_ws, size_t ws_size,
                              hipStream_t stream) {
  h16* wsw = (h16*)d_ws;
  auto conv = [&](int idx, int Ksrc, int N, int Kp, int p, int npad, int rot, size_t off) {
    int nfrags = (Kp / 16) * (N / 32);
    int total = nfrags * 64;
    convw_kernel<<<(total + 255) / 256, 256, 0, stream>>>(
        (const float*)d_in[idx], wsw + off, Ksrc, N, Kp, p, npad, rot);
  };
  conv(2, 63, 256, 64, 63, 1, 0, OFF_P0);
  conv(4, 256, 256, 256, 256, 0, 0, OFF_P1);
  conv(6, 256, 256, 256, 256, 0, 0, OFF_P2);
  conv(8, 256, 256, 256, 256, 0, 0, OFF_P3);
  conv(10, 256, 256, 256, 256, 0, 0, OFF_P4);
  conv(12, 319, 256, 320, 63, 1, 64, OFF_P5);   // rotated: h-part first
  conv(14, 256, 256, 256, 256, 0, 0, OFF_P6);
  conv(16, 256, 256, 256, 256, 0, 0, OFF_P7);
  conv(20, 256, 256, 256, 256, 0, 0, OFF_FEAT);
  conv(18, 283, 128, 288, 283, 5, 0, OFF_VIEWS);

  Params P;
  P.pts = (const float*)d_in[0];
  P.views = (const float*)d_in[1];
  P.wf = wsw;
  for (int i = 0; i < 8; ++i) P.pb[i] = (const float*)d_in[3 + 2 * i];
  P.views_b = (const float*)d_in[19];
  P.feat_b = (const float*)d_in[21];
  P.alpha_w = (const float*)d_in[22];
  P.alpha_b = (const float*)d_in[23];
  P.rgb_w = (const float*)d_in[24];
  P.rgb_b = (const float*)d_in[25];
  P.out = (float*)d_out;

  nerf_kernel<<<2048, 1024, 0, stream>>>(P);
}